// Round 17
// baseline (149.986 us; speedup 1.0000x reference)
//
#include <hip/hip_runtime.h>
#include <hip/hip_bf16.h>
#include <stdint.h>

typedef __attribute__((ext_vector_type(8))) short short8;
typedef __attribute__((ext_vector_type(8))) unsigned short ushort8;
typedef __attribute__((ext_vector_type(4))) unsigned short ushort4v;
typedef __attribute__((ext_vector_type(4))) unsigned u32x4;
typedef __attribute__((ext_vector_type(2))) float f32x2;
typedef __attribute__((ext_vector_type(4))) float f32x4;
typedef __attribute__((ext_vector_type(16))) float f32x16;

#define B_ 8
#define N_ 4096
#define C_ 256
#define D_ 32
#define LOG2E 1.44269504088896f

__device__ inline unsigned short f2bf(float f) {
  union { float f; unsigned u; } v; v.f = f;
  unsigned r = v.u + 0x7fffu + ((v.u >> 16) & 1u);
  return (unsigned short)(r >> 16);
}
__device__ inline float bf2f(unsigned short u) {
  return __uint_as_float(((unsigned)u) << 16);
}
__device__ inline float exp2_fast(float x) {
  float r; asm("v_exp_f32 %0, %1" : "=v"(r) : "v"(x)); return r;
}
__device__ inline unsigned cvt_pk_bf16(float lo, float hi) {
  unsigned r; asm("v_cvt_pk_bf16_f32 %0, %1, %2" : "=v"(r) : "v"(lo), "v"(hi)); return r;
}
// a <- [a.l0-31 | b.l0-31], b <- [a.l32-63 | b.l32-63]
__device__ inline void permlane32_swap(unsigned& a, unsigned& b) {
  asm volatile("v_permlane32_swap_b32 %0, %1" : "+v"(a), "+v"(b));
}
__device__ inline void gll16(const unsigned short* src, void* lds) {
  __builtin_amdgcn_global_load_lds((const __attribute__((address_space(1))) void*)src,
                                   (__attribute__((address_space(3))) void*)lds, 16, 0, 0);
}

// wf layout (fragment-major): B-frag for (col-tile ct, k-step s) of the 320x256
// combined weight: element (col C = ct*16+cl, k = s*32+gf*8+j) lives at
// wf[((ct*8+s)*64 + gf*16+cl)*8 + j]. A wave's B-load = 64 lanes x 16B contiguous.
__device__ inline size_t wf_addr(int C, int kk) {
  int ct = C >> 4, cl = C & 15, s = kk >> 5, gf = (kk >> 3) & 3, j = kk & 7;
  return ((size_t)((ct * 8 + s) * 64 + gf * 16 + cl)) * 8 + j;
}

// ---------------- kernel 0: FUSED weight prep ----------------
// blocks 0-63: cast w_q^T*log2e | w_k^T into wf tiles 0-3.
// blocks 64-67: Wvo^T = Wo^T . Wv^T GEMM reading wo/wv fp32 DIRECTLY (inline
// bf16 cvt), writing wf tiles 4-19 fragment-major.
__global__ __launch_bounds__(256) void prep_kernel(const float* __restrict__ wq,
                                                   const float* __restrict__ wk,
                                                   const float* __restrict__ wo,
                                                   const float* __restrict__ wv,
                                                   unsigned short* __restrict__ wf) {
  const int blk = blockIdx.x;
  if (blk < 64) {
    int i = blk * 256 + threadIdx.x;  // 16384 total
    int C = i >> 8, kk = i & 255;
    float v = (C < 32) ? wq[kk * 32 + C] * LOG2E : wk[kk * 32 + (C - 32)];
    wf[wf_addr(C, kk)] = f2bf(v);
  } else {
    const int lane = threadIdx.x & 63, w = threadIdx.x >> 6;
    const int g = lane >> 4, li = lane & 15;
    const int m0 = (blk - 64) * 64 + w * 16;
    f32x4 acc[16] = {};
    for (int kk = 0; kk < 256; kk += 32) {
      // A-frag: woT[m0+li][kk+g*8+e] = wo[(kk+g*8+e)*256 + m0+li] (scattered fp32)
      short8 a;
#pragma unroll
      for (int e = 0; e < 8; ++e)
        a[e] = (short)f2bf(wo[(size_t)(kk + g * 8 + e) * 256 + (m0 + li)]);
#pragma unroll
      for (int ct = 0; ct < 16; ++ct) {
        const float* bsrc = wv + (size_t)(ct * 16 + li) * 256 + kk + g * 8;
        f32x4 b0 = *reinterpret_cast<const f32x4*>(bsrc);
        f32x4 b1 = *reinterpret_cast<const f32x4*>(bsrc + 4);
        union { unsigned u[4]; short8 v; } Bf;
        Bf.u[0] = cvt_pk_bf16(b0[0], b0[1]); Bf.u[1] = cvt_pk_bf16(b0[2], b0[3]);
        Bf.u[2] = cvt_pk_bf16(b1[0], b1[1]); Bf.u[3] = cvt_pk_bf16(b1[2], b1[3]);
        acc[ct] = __builtin_amdgcn_mfma_f32_16x16x32_bf16(a, Bf.v, acc[ct], 0, 0, 0);
      }
    }
#pragma unroll
    for (int ct = 0; ct < 16; ++ct)
#pragma unroll
      for (int r = 0; r < 4; ++r) {
        const int C = 64 + m0 + (g << 2) + r;
        const int kk = ct * 16 + li;
        wf[wf_addr(C, kk)] = f2bf(acc[ct][r]);
      }
  }
}

// ---------------- kernel 1: fused QKVW projection (32-row blocks, 3 waves/SIMD) ----
// grid 1024 x 256; block = 32 rows x 320 cols. x staged ONCE in LDS (16KB,
// swizzled); W read fragment-major as coalesced 1KB B-loads into registers,
// double-buffered, counted vmcnt(5). Wave = 32 rows x 80 cols: per step 2 A
// ds_reads + 5 B reg-loads + 10 MFMAs. ONE barrier total. acc = 40 AGPR ->
// 3 waves/SIMD (launch_bounds(256,3)), 3 blocks/CU.
__global__ __launch_bounds__(256, 3) void qkv_kernel(const float* __restrict__ x,
                                                     const unsigned short* __restrict__ wf,
                                                     unsigned short* __restrict__ q,
                                                     unsigned short* __restrict__ k,
                                                     unsigned short* __restrict__ vwT) {
  __shared__ __align__(16) unsigned short xs[32 * 256];  // 16KB, swizzled
  const int tid = threadIdx.x;
  const int l = tid & 63, w = tid >> 6;
  const int bx = blockIdx.x;
  const int g = l >> 4, li = l & 15;
  const int m0 = bx * 32;

  // ---- issue all x loads first (oldest in vm queue) ----
  f32x4 xf[8];
#pragma unroll
  for (int r2 = 0; r2 < 4; ++r2) {
    const int idx8 = r2 * 256 + tid;        // 8-elem block index
    const int row = idx8 >> 5, xb = idx8 & 31;
    const float* src = x + (size_t)(m0 + row) * 256 + xb * 8;
    xf[2 * r2]     = *reinterpret_cast<const f32x4*>(src);
    xf[2 * r2 + 1] = *reinterpret_cast<const f32x4*>(src + 4);
  }
  __builtin_amdgcn_sched_barrier(0);  // keep x loads older than W loads

  const unsigned short* wfb = wf + (size_t)(w * 5) * 4096;  // wave's 5 col-tiles
  short8 BA[5], BB[5];
#pragma unroll
  for (int c = 0; c < 5; ++c)
    BA[c] = *reinterpret_cast<const short8*>(wfb + ((size_t)(c * 8 + 0) * 64 + l) * 8);
#pragma unroll
  for (int c = 0; c < 5; ++c)
    BB[c] = *reinterpret_cast<const short8*>(wfb + ((size_t)(c * 8 + 1) * 64 + l) * 8);

  // ---- stage x -> bf16 LDS (cvt waits drain x loads only; W loads are newer) ----
#pragma unroll
  for (int r2 = 0; r2 < 4; ++r2) {
    const int idx8 = r2 * 256 + tid;
    const int row = idx8 >> 5, xb = idx8 & 31;
    union { unsigned u[4]; ushort8 v; } P;
    P.u[0] = cvt_pk_bf16(xf[2 * r2][0], xf[2 * r2][1]);
    P.u[1] = cvt_pk_bf16(xf[2 * r2][2], xf[2 * r2][3]);
    P.u[2] = cvt_pk_bf16(xf[2 * r2 + 1][0], xf[2 * r2 + 1][1]);
    P.u[3] = cvt_pk_bf16(xf[2 * r2 + 1][2], xf[2 * r2 + 1][3]);
    *reinterpret_cast<ushort8*>(&xs[row * 256 + ((xb ^ (row & 7)) << 3)]) = P.v;
  }
  __syncthreads();  // xs ready; read-only hereafter

  f32x4 acc[2][5] = {};

#define QSTEP(S, BV, WN, PREF)                                                       \
  {                                                                                  \
    asm volatile("s_waitcnt vmcnt(" WN ")" ::: "memory");                            \
    __builtin_amdgcn_sched_barrier(0);                                               \
    short8 a_[2];                                                                    \
    _Pragma("unroll") for (int mt = 0; mt < 2; ++mt) {                               \
      const int row = mt * 16 + li;                                                  \
      a_[mt] = *reinterpret_cast<const short8*>(                                     \
          xs + row * 256 + ((((S) * 4 + g) ^ (row & 7)) << 3));                      \
    }                                                                                \
    _Pragma("unroll") for (int mt = 0; mt < 2; ++mt)                                 \
        _Pragma("unroll") for (int c = 0; c < 5; ++c)                                \
            acc[mt][c] = __builtin_amdgcn_mfma_f32_16x16x32_bf16(a_[mt], BV[c],      \
                                                                 acc[mt][c], 0, 0, 0); \
    if (PREF) {                                                                      \
      _Pragma("unroll") for (int c = 0; c < 5; ++c)                                  \
          BV[c] = *reinterpret_cast<const short8*>(                                  \
              wfb + ((size_t)(c * 8 + (S) + 2) * 64 + l) * 8);                       \
    }                                                                                \
  }

  QSTEP(0, BA, "5", true)
  QSTEP(1, BB, "5", true)
  QSTEP(2, BA, "5", true)
  QSTEP(3, BB, "5", true)
  QSTEP(4, BA, "5", true)
  QSTEP(5, BB, "5", true)
  QSTEP(6, BA, "5", false)
  QSTEP(7, BB, "0", false)
#undef QSTEP

  // ---- stores: wave w owns col-tiles w*5..w*5+4 over rows m0..m0+31 ----
  const int bb_ = bx >> 7;
#pragma unroll
  for (int mt = 0; mt < 2; ++mt) {
    const int nloc = (bx & 127) * 32 + mt * 16 + (g << 2);
#pragma unroll
    for (int c = 0; c < 5; ++c) {
      const int Cg = w * 5 + c;
      if (Cg < 2) {        // q cols 0-31
        const int col = Cg * 16 + li;
#pragma unroll
        for (int r = 0; r < 4; ++r)
          q[((size_t)bb_ * N_ + nloc + r) * D_ + col] = f2bf(acc[mt][c][r]);
      } else if (Cg < 4) {  // k cols 0-31
        const int col = (Cg - 2) * 16 + li;
#pragma unroll
        for (int r = 0; r < 4; ++r)
          k[((size_t)bb_ * N_ + nloc + r) * D_ + col] = f2bf(acc[mt][c][r]);
      } else {              // vwT channel
        const int vc = Cg * 16 + li - 64;
        union { unsigned u[2]; ushort4v v; } P;
        P.u[0] = cvt_pk_bf16(acc[mt][c][0], acc[mt][c][1]);
        P.u[1] = cvt_pk_bf16(acc[mt][c][2], acc[mt][c][3]);
        *reinterpret_cast<ushort4v*>(&vwT[((size_t)bb_ * C_ + vc) * N_ + nloc]) = P.v;
      }
    }
  }
}

// ---------------- kernel 2: flash attention (r16, frozen) ----------
__global__ __launch_bounds__(512, 2) void flash_kernel(const unsigned short* __restrict__ q,
                                                       const unsigned short* __restrict__ k,
                                                       const unsigned short* __restrict__ vwT,
                                                       const float* __restrict__ x,
                                                       float* __restrict__ out) {
  __shared__ __align__(16) char smem[147456];  // V 2grp x 2buf x 32KB | K @131072 2x2x4KB
  const int tid = threadIdx.x;
  const int l = tid & 63, w_ = tid >> 6;       // 0..7
  const int kvh = w_ >> 2, qg = w_ & 3;
  const int blk = blockIdx.x;
  const int b = blk & 7;
  const int qt = blk >> 3;                     // 0..31
  const int h = l >> 5, l31 = l & 31;
  const int R = kvh * 65536;

  const unsigned short* kb_ = k + (size_t)b * N_ * D_;
  const unsigned short* vb_ = vwT + (size_t)b * C_ * N_;

  const int qposb = qt * 128 + qg * 32;  // + l31
  const size_t qoff = ((size_t)b * N_ + qposb + l31) * D_ + h * 8;
  const short8 qb0 = *reinterpret_cast<const short8*>(q + qoff);
  const short8 qb1 = *reinterpret_cast<const short8*>(q + qoff + 16);
  asm volatile("s_waitcnt vmcnt(0)" ::: "memory");  // clean vm counter before staging

  const int vrow = l >> 3;
  const int vsrc = ((l & 7) ^ ((l >> 3) & 7)) << 3;  // elems
  const int krow = l >> 2;
  const int ksrc = ((l & 3) ^ ((l >> 3) & 3)) << 3;  // elems
  const int kvbase = kvh * 2048;

#define STAGE(BUF, KV0)                                                           \
  {                                                                               \
    char* vd = smem + R + (BUF) * 32768 + qg * 8192;                              \
    _Pragma("unroll") for (int t = 0; t < 8; ++t)                                 \
        gll16(vb_ + (size_t)(qg * 64 + t * 8 + vrow) * N_ + (KV0) + vsrc,         \
              vd + t * 1024);                                                     \
    gll16(kb_ + (size_t)((KV0) + qg * 16 + krow) * D_ + ksrc,                     \
          smem + 131072 + kvh * 8192 + (BUF) * 4096 + qg * 1024);                 \
  }

  f32x16 o[8] = {};  // [ct]: O^T (32c x 32q), c = ct*32 + ...
  float lsum = 0.f;
  const f32x16 z16 = {};
  const int kkey = (l31 >> 1) & 3;

  STAGE(0, kvbase)

  for (int i = 0; i < 32; ++i) {
    const int buf = i & 1;
    asm volatile("s_waitcnt vmcnt(0)" ::: "memory");  // chunk i landed (1 iter ago)
    __builtin_amdgcn_sched_barrier(0);
    __builtin_amdgcn_s_barrier();  // all waves' chunk-i loads landed; buf^1 reads done
    if (i < 31) STAGE(buf ^ 1, kvbase + (i + 1) * 64)
    const char* Vb = smem + R + buf * 32768;
    const char* Kb = smem + 131072 + kvh * 8192 + buf * 4096;
#pragma unroll
    for (int kvt = 0; kvt < 2; ++kvt) {
      const int krow32 = (kvt * 32 + l31) * 64;
      short8 ka0 = *reinterpret_cast<const short8*>(Kb + krow32 + (((0 + h) ^ kkey) << 4));
      short8 ka1 = *reinterpret_cast<const short8*>(Kb + krow32 + (((2 + h) ^ kkey) << 4));
      f32x16 s = __builtin_amdgcn_mfma_f32_32x32x16_bf16(ka0, qb0, z16, 0, 0, 0);
      s = __builtin_amdgcn_mfma_f32_32x32x16_bf16(ka1, qb1, s, 0, 0, 0);
#pragma unroll
      for (int r = 0; r < 16; ++r) s[r] = exp2_fast(s[r]);
      lsum += (((s[0] + s[1]) + (s[2] + s[3])) + ((s[4] + s[5]) + (s[6] + s[7]))) +
              (((s[8] + s[9]) + (s[10] + s[11])) + ((s[12] + s[13]) + (s[14] + s[15])));
      short8 pf0, pf1;
      {
        unsigned x0 = cvt_pk_bf16(s[0], s[1]),   y0 = cvt_pk_bf16(s[4], s[5]);
        unsigned x1 = cvt_pk_bf16(s[2], s[3]),   y1 = cvt_pk_bf16(s[6], s[7]);
        unsigned x2 = cvt_pk_bf16(s[8], s[9]),   y2 = cvt_pk_bf16(s[12], s[13]);
        unsigned x3 = cvt_pk_bf16(s[10], s[11]), y3 = cvt_pk_bf16(s[14], s[15]);
        permlane32_swap(x0, y0); permlane32_swap(x1, y1);
        permlane32_swap(x2, y2); permlane32_swap(x3, y3);
        union U { unsigned u[4]; short8 v; };
        U u0; u0.u[0] = x0; u0.u[1] = x1; u0.u[2] = y0; u0.u[3] = y1;  // kv 0-15
        U u1; u1.u[0] = x2; u1.u[1] = x3; u1.u[2] = y2; u1.u[3] = y3;  // kv 16-31
        pf0 = u0.v; pf1 = u1.v;
      }
      __builtin_amdgcn_s_setprio(1);
#pragma unroll
      for (int ct = 0; ct < 8; ++ct) {
        const int rl = ct * 32 + l31;
        const int vkey = rl & 7;
        const int rb = rl * 128;
        short8 va0 = *reinterpret_cast<const short8*>(Vb + rb + (((kvt * 4 + 0 + h) ^ vkey) << 4));
        short8 va1 = *reinterpret_cast<const short8*>(Vb + rb + (((kvt * 4 + 2 + h) ^ vkey) << 4));
        o[ct] = __builtin_amdgcn_mfma_f32_32x32x16_bf16(va0, pf0, o[ct], 0, 0, 0);
        o[ct] = __builtin_amdgcn_mfma_f32_32x32x16_bf16(va1, pf1, o[ct], 0, 0, 0);
      }
      __builtin_amdgcn_s_setprio(0);
    }
  }

  // ---- in-block kv-merge + normalize + residual + final store ----
  lsum += __shfl_xor(lsum, 32);
  __syncthreads();  // final chunk reads complete; LDS reusable
  float* lb = reinterpret_cast<float*>(smem + 131072);  // lsums[2][4][32] in K region
  if (h == 0) lb[kvh * 128 + qg * 32 + l31] = lsum;
  if (kvh == 1) {
    char* ob = smem + qg * 16384;  // wave slot: 64 bf16-pairs/lane, b128 lane-major
    int pg = 0;
#pragma unroll
    for (int ct = 0; ct < 8; ++ct)
#pragma unroll
      for (int jg = 0; jg < 2; ++jg) {
        u32x4 t;
#pragma unroll
        for (int e = 0; e < 4; ++e) {
          const int j = jg * 4 + e;
          t[e] = cvt_pk_bf16(o[ct][2 * j], o[ct][2 * j + 1]);
        }
        *reinterpret_cast<u32x4*>(ob + pg * 1024 + l * 16) = t;
        ++pg;
      }
  }
  __syncthreads();
  if (kvh == 0) {
    const float inv = 1.0f / (lb[qg * 32 + l31] + lb[128 + qg * 32 + l31]);
    const char* ob = smem + qg * 16384;
    int pg = 0;
#pragma unroll
    for (int ct = 0; ct < 8; ++ct)
#pragma unroll
      for (int jg = 0; jg < 2; ++jg) {
        u32x4 t = *reinterpret_cast<const u32x4*>(ob + pg * 1024 + l * 16);
        ++pg;
#pragma unroll
        for (int e = 0; e < 4; ++e) {
          const int j = jg * 4 + e;
          o[ct][2 * j]     += bf2f((unsigned short)(t[e] & 0xffffu));
          o[ct][2 * j + 1] += bf2f((unsigned short)(t[e] >> 16));
        }
      }
    const size_t rowbase = ((size_t)b * N_ + qposb + l31) * C_;
#pragma unroll
    for (int ct = 0; ct < 8; ++ct)
#pragma unroll
      for (int j = 0; j < 8; ++j) {
        const int c = ct * 32 + 2 * (j & 1) + 8 * (j >> 1) + 4 * h;
        f32x2 xr = *reinterpret_cast<const f32x2*>(x + rowbase + c);
        f32x2 t;
        t[0] = o[ct][2 * j] * inv + xr[0];
        t[1] = o[ct][2 * j + 1] * inv + xr[1];
        *reinterpret_cast<f32x2*>(out + rowbase + c) = t;
      }
  }
#undef STAGE
}

extern "C" void kernel_launch(void* const* d_in, const int* in_sizes, int n_in,
                              void* d_out, int out_size, void* d_ws, size_t ws_size,
                              hipStream_t stream) {
  const float* x  = (const float*)d_in[0];
  const float* wq = (const float*)d_in[1];
  const float* wk = (const float*)d_in[2];
  const float* wv = (const float*)d_in[3];
  const float* wo = (const float*)d_in[4];
  float* out = (float*)d_out;
  char* ws = (char*)d_ws;
  unsigned short* wf  = (unsigned short*)(ws + 0);        // 163840 B (frag-major W)
  unsigned short* q   = (unsigned short*)(ws + 163840);   // 2 MB
  unsigned short* k   = (unsigned short*)(ws + 2260992);  // 2 MB
  unsigned short* vwT = (unsigned short*)(ws + 4358144);  // 16 MB (total ~20.1 MB)

  prep_kernel<<<68, 256, 0, stream>>>(wq, wk, wo, wv, wf);
  qkv_kernel<<<1024, 256, 0, stream>>>(x, wf, q, k, vwT);
  flash_kernel<<<256, 512, 0, stream>>>(q, k, vwT, x, out);
}

// Round 18
// 125.458 us; speedup vs baseline: 1.1955x; 1.1955x over previous
//
#include <hip/hip_runtime.h>
#include <hip/hip_bf16.h>
#include <stdint.h>

typedef __attribute__((ext_vector_type(8))) short short8;
typedef __attribute__((ext_vector_type(8))) unsigned short ushort8;
typedef __attribute__((ext_vector_type(4))) unsigned short ushort4v;
typedef __attribute__((ext_vector_type(4))) unsigned u32x4;
typedef __attribute__((ext_vector_type(2))) float f32x2;
typedef __attribute__((ext_vector_type(4))) float f32x4;
typedef __attribute__((ext_vector_type(16))) float f32x16;

#define B_ 8
#define N_ 4096
#define C_ 256
#define D_ 32
#define LOG2E 1.44269504088896f

__device__ inline unsigned short f2bf(float f) {
  union { float f; unsigned u; } v; v.f = f;
  unsigned r = v.u + 0x7fffu + ((v.u >> 16) & 1u);
  return (unsigned short)(r >> 16);
}
__device__ inline float bf2f(unsigned short u) {
  return __uint_as_float(((unsigned)u) << 16);
}
__device__ inline float exp2_fast(float x) {
  float r; asm("v_exp_f32 %0, %1" : "=v"(r) : "v"(x)); return r;
}
__device__ inline unsigned cvt_pk_bf16(float lo, float hi) {
  unsigned r; asm("v_cvt_pk_bf16_f32 %0, %1, %2" : "=v"(r) : "v"(lo), "v"(hi)); return r;
}
// a <- [a.l0-31 | b.l0-31], b <- [a.l32-63 | b.l32-63]
__device__ inline void permlane32_swap(unsigned& a, unsigned& b) {
  asm volatile("v_permlane32_swap_b32 %0, %1" : "+v"(a), "+v"(b));
}
__device__ inline void gll16(const unsigned short* src, void* lds) {
  __builtin_amdgcn_global_load_lds((const __attribute__((address_space(1))) void*)src,
                                   (__attribute__((address_space(3))) void*)lds, 16, 0, 0);
}

// wf layout (fragment-major): B-frag for (col-tile ct, k-step s) of the 320x256
// combined weight: element (col C = ct*16+cl, k = s*32+gf*8+j) lives at
// wf[((ct*8+s)*64 + gf*16+cl)*8 + j]. A wave's B-load = 64 lanes x 16B contiguous.
__device__ inline size_t wf_addr(int C, int kk) {
  int ct = C >> 4, cl = C & 15, s = kk >> 5, gf = (kk >> 3) & 3, j = kk & 7;
  return ((size_t)((ct * 8 + s) * 64 + gf * 16 + cl)) * 8 + j;
}

// ---------------- kernel 0a: weight casts ----------------
__global__ __launch_bounds__(256) void prep_kernel(const float* __restrict__ wq,
                                                   const float* __restrict__ wk,
                                                   const float* __restrict__ wo,
                                                   const float* __restrict__ wv,
                                                   unsigned short* __restrict__ wf,
                                                   unsigned short* __restrict__ wv_b,
                                                   unsigned short* __restrict__ woT_b) {
  int i = blockIdx.x * 256 + threadIdx.x;  // total 147456
  if (i < 16384) {
    int C = i >> 8, kk = i & 255;
    float v = (C < 32) ? wq[kk * 32 + C] * LOG2E : wk[kk * 32 + (C - 32)];
    wf[wf_addr(C, kk)] = f2bf(v);
  } else if (i < 81920) {
    int j = i - 16384;
    wv_b[j] = f2bf(wv[j]);
  } else {
    int j = i - 81920;  // woT_b[e2][e] = wo[e][e2]
    int e2 = j >> 8, e = j & 255;
    woT_b[j] = f2bf(wo[e * 256 + e2]);
  }
}

// ---------------- kernel 0b: Wvo^T = Wo^T . Wv^T -> wf tiles 4-19 (fragment-major) --
__global__ __launch_bounds__(256) void prep2_kernel(const unsigned short* __restrict__ woT_b,
                                                    const unsigned short* __restrict__ wv_b,
                                                    unsigned short* __restrict__ wf) {
  const int lane = threadIdx.x & 63, w = threadIdx.x >> 6;
  const int g = lane >> 4, li = lane & 15;
  const int m0 = blockIdx.x * 64 + w * 16;
  const unsigned short* arow = woT_b + (size_t)(m0 + li) * 256 + (g << 3);
  const unsigned short* brow = wv_b + (size_t)li * 256 + (g << 3);
  f32x4 acc[16] = {};
  for (int kk = 0; kk < 256; kk += 32) {
    short8 a = *reinterpret_cast<const short8*>(arow + kk);
#pragma unroll
    for (int ct = 0; ct < 16; ++ct) {
      short8 bb = *reinterpret_cast<const short8*>(brow + (size_t)ct * 16 * 256 + kk);
      acc[ct] = __builtin_amdgcn_mfma_f32_16x16x32_bf16(a, bb, acc[ct], 0, 0, 0);
    }
  }
#pragma unroll
  for (int ct = 0; ct < 16; ++ct)
#pragma unroll
    for (int r = 0; r < 4; ++r) {
      const int C = 64 + m0 + (g << 2) + r;
      const int kk = ct * 16 + li;
      wf[wf_addr(C, kk)] = f2bf(acc[ct][r]);
    }
}

// ---------------- kernel 1: fused QKVW projection (r13, validated) ----------------
__global__ __launch_bounds__(256, 2) void qkv_kernel(const float* __restrict__ x,
                                                     const unsigned short* __restrict__ wf,
                                                     unsigned short* __restrict__ q,
                                                     unsigned short* __restrict__ k,
                                                     unsigned short* __restrict__ vwT) {
  __shared__ __align__(16) unsigned short xs[64 * 256];  // 32KB, swizzled
  const int tid = threadIdx.x;
  const int l = tid & 63, w = tid >> 6;
  const int bx = blockIdx.x;
  const int g = l >> 4, li = l & 15;
  const int m0 = bx * 64;

  const unsigned short* wfb = wf + (size_t)(w * 5) * 4096;  // wave's 5 col-tiles

  short8 BA[5], BB[5];
#pragma unroll
  for (int c = 0; c < 5; ++c)
    BA[c] = *reinterpret_cast<const short8*>(wfb + ((size_t)(c * 8 + 0) * 64 + l) * 8);
#pragma unroll
  for (int c = 0; c < 5; ++c)
    BB[c] = *reinterpret_cast<const short8*>(wfb + ((size_t)(c * 8 + 1) * 64 + l) * 8);

  {
    const int row = tid >> 2, qtr = tid & 3;
    const float* src = x + (size_t)(m0 + row) * 256 + qtr * 64;
    unsigned short* dstrow = xs + row * 256;
#pragma unroll
    for (int jj = 0; jj < 8; ++jj) {
      f32x4 a0 = *reinterpret_cast<const f32x4*>(src + jj * 8);
      f32x4 a1 = *reinterpret_cast<const f32x4*>(src + jj * 8 + 4);
      union { unsigned u[4]; ushort8 v; } P;
      P.u[0] = cvt_pk_bf16(a0[0], a0[1]); P.u[1] = cvt_pk_bf16(a0[2], a0[3]);
      P.u[2] = cvt_pk_bf16(a1[0], a1[1]); P.u[3] = cvt_pk_bf16(a1[2], a1[3]);
      const int blk = (qtr * 8 + jj) ^ (row & 7);
      *reinterpret_cast<ushort8*>(dstrow + blk * 8) = P.v;
    }
  }
  __syncthreads();  // xs ready; read-only hereafter

  f32x4 acc[4][5] = {};

#define QSTEP(S, BV, WN, PREF)                                                       \
  {                                                                                  \
    asm volatile("s_waitcnt vmcnt(" WN ")" ::: "memory");                            \
    __builtin_amdgcn_sched_barrier(0);                                               \
    short8 a_[4];                                                                    \
    _Pragma("unroll") for (int mt = 0; mt < 4; ++mt) {                               \
      const int row = mt * 16 + li;                                                  \
      a_[mt] = *reinterpret_cast<const short8*>(                                     \
          xs + row * 256 + ((((S) * 4 + g) ^ (row & 7)) << 3));                      \
    }                                                                                \
    _Pragma("unroll") for (int mt = 0; mt < 4; ++mt)                                 \
        _Pragma("unroll") for (int c = 0; c < 5; ++c)                                \
            acc[mt][c] = __builtin_amdgcn_mfma_f32_16x16x32_bf16(a_[mt], BV[c],      \
                                                                 acc[mt][c], 0, 0, 0); \
    if (PREF) {                                                                      \
      _Pragma("unroll") for (int c = 0; c < 5; ++c)                                  \
          BV[c] = *reinterpret_cast<const short8*>(                                  \
              wfb + ((size_t)(c * 8 + (S) + 2) * 64 + l) * 8);                       \
    }                                                                                \
  }

  QSTEP(0, BA, "5", true)
  QSTEP(1, BB, "5", true)
  QSTEP(2, BA, "5", true)
  QSTEP(3, BB, "5", true)
  QSTEP(4, BA, "5", true)
  QSTEP(5, BB, "5", true)
  QSTEP(6, BA, "5", false)
  QSTEP(7, BB, "0", false)
#undef QSTEP

  const int bb_ = bx >> 6;
#pragma unroll
  for (int mt = 0; mt < 4; ++mt) {
    const int nloc = (bx & 63) * 64 + mt * 16 + (g << 2);
#pragma unroll
    for (int c = 0; c < 5; ++c) {
      const int Cg = w * 5 + c;
      if (Cg < 2) {
        const int col = Cg * 16 + li;
#pragma unroll
        for (int r = 0; r < 4; ++r)
          q[((size_t)bb_ * N_ + nloc + r) * D_ + col] = f2bf(acc[mt][c][r]);
      } else if (Cg < 4) {
        const int col = (Cg - 2) * 16 + li;
#pragma unroll
        for (int r = 0; r < 4; ++r)
          k[((size_t)bb_ * N_ + nloc + r) * D_ + col] = f2bf(acc[mt][c][r]);
      } else {
        const int vc = Cg * 16 + li - 64;
        union { unsigned u[2]; ushort4v v; } P;
        P.u[0] = cvt_pk_bf16(acc[mt][c][0], acc[mt][c][1]);
        P.u[1] = cvt_pk_bf16(acc[mt][c][2], acc[mt][c][3]);
        *reinterpret_cast<ushort4v*>(&vwT[((size_t)bb_ * C_ + vc) * N_ + nloc]) = P.v;
      }
    }
  }
}

// ---------------- kernel 2: flash attention, de-duplicated S (32q x 256c waves) ----
// grid 256 x 512. blk: b = blk&7 (XCD pin), qt = blk>>3 (0..31). 8 waves:
// kvh = w>>2 (2048-kv half), qg = w&3 (DISTINCT 32q strip). Each wave computes S
// for its own strip exactly once and the FULL 256c PV (acc = 8 x f32x16 = 128
// AGPR). V[256c][64kv] dbuf (2x32KB) + K[64kv][32d] (2x4KB) per kvh group; per
// iter (32): vmcnt(0) -> s_barrier -> stage chunk i+1 (uniform 9 gll16/wave) ->
// two 32-kv sub-bodies. In-block kv-merge + normalize + residual + fp32 store.
__global__ __launch_bounds__(512, 2) void flash_kernel(const unsigned short* __restrict__ q,
                                                       const unsigned short* __restrict__ k,
                                                       const unsigned short* __restrict__ vwT,
                                                       const float* __restrict__ x,
                                                       float* __restrict__ out) {
  __shared__ __align__(16) char smem[147456];  // V 2grp x 2buf x 32KB | K @131072 2x2x4KB
  const int tid = threadIdx.x;
  const int l = tid & 63, w_ = tid >> 6;       // 0..7
  const int kvh = w_ >> 2, qg = w_ & 3;
  const int blk = blockIdx.x;
  const int b = blk & 7;
  const int qt = blk >> 3;                     // 0..31
  const int h = l >> 5, l31 = l & 31;
  const int R = kvh * 65536;

  const unsigned short* kb_ = k + (size_t)b * N_ * D_;
  const unsigned short* vb_ = vwT + (size_t)b * C_ * N_;

  // Q B-frags: col q = l31, k-dim = ks*16 + 8h + j  (one 32q strip per wave)
  const int qposb = qt * 128 + qg * 32;  // + l31
  const size_t qoff = ((size_t)b * N_ + qposb + l31) * D_ + h * 8;
  const short8 qb0 = *reinterpret_cast<const short8*>(q + qoff);
  const short8 qb1 = *reinterpret_cast<const short8*>(q + qoff + 16);
  asm volatile("s_waitcnt vmcnt(0)" ::: "memory");  // clean vm counter before staging

  // V staging: wave qg stages channels qg*64..+63; granule t = 8 rows x 128B;
  // lane -> (row = l>>3, 16B-pos = l&7); source block = (l&7) ^ (row&7).
  const int vrow = l >> 3;
  const int vsrc = ((l & 7) ^ ((l >> 3) & 7)) << 3;  // elems
  // K staging: wave qg stages kv rows qg*16..+15; lane -> (row = l>>2, pos = l&3).
  const int krow = l >> 2;
  const int ksrc = ((l & 3) ^ ((l >> 3) & 3)) << 3;  // elems
  const int kvbase = kvh * 2048;

#define STAGE(BUF, KV0)                                                           \
  {                                                                               \
    char* vd = smem + R + (BUF) * 32768 + qg * 8192;                              \
    _Pragma("unroll") for (int t = 0; t < 8; ++t)                                 \
        gll16(vb_ + (size_t)(qg * 64 + t * 8 + vrow) * N_ + (KV0) + vsrc,         \
              vd + t * 1024);                                                     \
    gll16(kb_ + (size_t)((KV0) + qg * 16 + krow) * D_ + ksrc,                     \
          smem + 131072 + kvh * 8192 + (BUF) * 4096 + qg * 1024);                 \
  }

  f32x16 o[8] = {};  // [ct]: O^T (32c x 32q), c = ct*32 + ...
  float lsum = 0.f;
  const f32x16 z16 = {};
  const int kkey = (l31 >> 1) & 3;

  STAGE(0, kvbase)

  for (int i = 0; i < 32; ++i) {
    const int buf = i & 1;
    asm volatile("s_waitcnt vmcnt(0)" ::: "memory");  // chunk i landed (1 iter ago)
    __builtin_amdgcn_sched_barrier(0);
    __builtin_amdgcn_s_barrier();  // all waves' chunk-i loads landed; buf^1 reads done
    if (i < 31) STAGE(buf ^ 1, kvbase + (i + 1) * 64)
    const char* Vb = smem + R + buf * 32768;
    const char* Kb = smem + 131072 + kvh * 8192 + buf * 4096;
#pragma unroll
    for (int kvt = 0; kvt < 2; ++kvt) {
      // ---- S^T = K.Q^T for kv sub-chunk kvt*32..+31 (this wave's 32q only) ----
      const int krow32 = (kvt * 32 + l31) * 64;
      short8 ka0 = *reinterpret_cast<const short8*>(Kb + krow32 + (((0 + h) ^ kkey) << 4));
      short8 ka1 = *reinterpret_cast<const short8*>(Kb + krow32 + (((2 + h) ^ kkey) << 4));
      f32x16 s = __builtin_amdgcn_mfma_f32_32x32x16_bf16(ka0, qb0, z16, 0, 0, 0);
      s = __builtin_amdgcn_mfma_f32_32x32x16_bf16(ka1, qb1, s, 0, 0, 0);
#pragma unroll
      for (int r = 0; r < 16; ++r) s[r] = exp2_fast(s[r]);
      lsum += (((s[0] + s[1]) + (s[2] + s[3])) + ((s[4] + s[5]) + (s[6] + s[7]))) +
              (((s[8] + s[9]) + (s[10] + s[11])) + ((s[12] + s[13]) + (s[14] + s[15])));
      short8 pf0, pf1;
      {
        unsigned x0 = cvt_pk_bf16(s[0], s[1]),   y0 = cvt_pk_bf16(s[4], s[5]);
        unsigned x1 = cvt_pk_bf16(s[2], s[3]),   y1 = cvt_pk_bf16(s[6], s[7]);
        unsigned x2 = cvt_pk_bf16(s[8], s[9]),   y2 = cvt_pk_bf16(s[12], s[13]);
        unsigned x3 = cvt_pk_bf16(s[10], s[11]), y3 = cvt_pk_bf16(s[14], s[15]);
        permlane32_swap(x0, y0); permlane32_swap(x1, y1);
        permlane32_swap(x2, y2); permlane32_swap(x3, y3);
        union U { unsigned u[4]; short8 v; };
        U u0; u0.u[0] = x0; u0.u[1] = x1; u0.u[2] = y0; u0.u[3] = y1;  // kv 0-15
        U u1; u1.u[0] = x2; u1.u[1] = x3; u1.u[2] = y2; u1.u[3] = y3;  // kv 16-31
        pf0 = u0.v; pf1 = u1.v;
      }
      // ---- PV over FULL 256c: O^T += V^T . P^T ----
      __builtin_amdgcn_s_setprio(1);
#pragma unroll
      for (int ct = 0; ct < 8; ++ct) {
        const int rl = ct * 32 + l31;
        const int vkey = rl & 7;
        const int rb = rl * 128;
        short8 va0 = *reinterpret_cast<const short8*>(Vb + rb + (((kvt * 4 + 0 + h) ^ vkey) << 4));
        short8 va1 = *reinterpret_cast<const short8*>(Vb + rb + (((kvt * 4 + 2 + h) ^ vkey) << 4));
        o[ct] = __builtin_amdgcn_mfma_f32_32x32x16_bf16(va0, pf0, o[ct], 0, 0, 0);
        o[ct] = __builtin_amdgcn_mfma_f32_32x32x16_bf16(va1, pf1, o[ct], 0, 0, 0);
      }
      __builtin_amdgcn_s_setprio(0);
    }
  }

  // ---- in-block kv-merge + normalize + residual + final store ----
  lsum += __shfl_xor(lsum, 32);
  __syncthreads();  // final chunk reads complete; LDS reusable
  float* lb = reinterpret_cast<float*>(smem + 131072);  // lsums[2][4][32] in K region
  if (h == 0) lb[kvh * 128 + qg * 32 + l31] = lsum;
  if (kvh == 1) {
    char* ob = smem + qg * 16384;  // wave slot: 64 bf16-pairs/lane, b128 lane-major
    int pg = 0;
#pragma unroll
    for (int ct = 0; ct < 8; ++ct)
#pragma unroll
      for (int jg = 0; jg < 2; ++jg) {
        u32x4 t;
#pragma unroll
        for (int e = 0; e < 4; ++e) {
          const int j = jg * 4 + e;
          t[e] = cvt_pk_bf16(o[ct][2 * j], o[ct][2 * j + 1]);
        }
        *reinterpret_cast<u32x4*>(ob + pg * 1024 + l * 16) = t;
        ++pg;
      }
  }
  __syncthreads();
  if (kvh == 0) {
    const float inv = 1.0f / (lb[qg * 32 + l31] + lb[128 + qg * 32 + l31]);
    const char* ob = smem + qg * 16384;
    int pg = 0;
#pragma unroll
    for (int ct = 0; ct < 8; ++ct)
#pragma unroll
      for (int jg = 0; jg < 2; ++jg) {
        u32x4 t = *reinterpret_cast<const u32x4*>(ob + pg * 1024 + l * 16);
        ++pg;
#pragma unroll
        for (int e = 0; e < 4; ++e) {
          const int j = jg * 4 + e;
          o[ct][2 * j]     += bf2f((unsigned short)(t[e] & 0xffffu));
          o[ct][2 * j + 1] += bf2f((unsigned short)(t[e] >> 16));
        }
      }
    const size_t rowbase = ((size_t)b * N_ + qposb + l31) * C_;
#pragma unroll
    for (int ct = 0; ct < 8; ++ct)
#pragma unroll
      for (int j = 0; j < 8; ++j) {
        const int c = ct * 32 + 2 * (j & 1) + 8 * (j >> 1) + 4 * h;
        f32x2 xr = *reinterpret_cast<const f32x2*>(x + rowbase + c);
        f32x2 t;
        t[0] = o[ct][2 * j] * inv + xr[0];
        t[1] = o[ct][2 * j + 1] * inv + xr[1];
        *reinterpret_cast<f32x2*>(out + rowbase + c) = t;
      }
  }
#undef STAGE
}

extern "C" void kernel_launch(void* const* d_in, const int* in_sizes, int n_in,
                              void* d_out, int out_size, void* d_ws, size_t ws_size,
                              hipStream_t stream) {
  const float* x  = (const float*)d_in[0];
  const float* wq = (const float*)d_in[1];
  const float* wk = (const float*)d_in[2];
  const float* wv = (const float*)d_in[3];
  const float* wo = (const float*)d_in[4];
  float* out = (float*)d_out;
  char* ws = (char*)d_ws;
  unsigned short* wf    = (unsigned short*)(ws + 0);         // 163840 B (frag-major W)
  unsigned short* wv_b  = (unsigned short*)(ws + 163840);    // 131072 B
  unsigned short* woT_b = (unsigned short*)(ws + 294912);    // 131072 B
  unsigned short* q     = (unsigned short*)(ws + 425984);    // 2 MB
  unsigned short* k     = (unsigned short*)(ws + 2523136);   // 2 MB
  unsigned short* vwT   = (unsigned short*)(ws + 4620288);   // 16 MB (total ~20.4 MB)

  prep_kernel<<<576, 256, 0, stream>>>(wq, wk, wo, wv, wf, wv_b, woT_b);
  prep2_kernel<<<4, 256, 0, stream>>>(woT_b, wv_b, wf);
  qkv_kernel<<<512, 256, 0, stream>>>(x, wf, q, k, vwT);
  flash_kernel<<<256, 512, 0, stream>>>(q, k, vwT, x, out);
}

// Round 19
// 111.777 us; speedup vs baseline: 1.3418x; 1.1224x over previous
//
#include <hip/hip_runtime.h>
#include <hip/hip_bf16.h>
#include <stdint.h>

typedef __attribute__((ext_vector_type(8))) short short8;
typedef __attribute__((ext_vector_type(8))) unsigned short ushort8;
typedef __attribute__((ext_vector_type(4))) unsigned short ushort4v;
typedef __attribute__((ext_vector_type(4))) unsigned u32x4;
typedef __attribute__((ext_vector_type(2))) float f32x2;
typedef __attribute__((ext_vector_type(4))) float f32x4;
typedef __attribute__((ext_vector_type(16))) float f32x16;

#define B_ 8
#define N_ 4096
#define C_ 256
#define D_ 32
#define LOG2E 1.44269504088896f

__device__ inline unsigned short f2bf(float f) {
  union { float f; unsigned u; } v; v.f = f;
  unsigned r = v.u + 0x7fffu + ((v.u >> 16) & 1u);
  return (unsigned short)(r >> 16);
}
__device__ inline float bf2f(unsigned short u) {
  return __uint_as_float(((unsigned)u) << 16);
}
__device__ inline float exp2_fast(float x) {
  float r; asm("v_exp_f32 %0, %1" : "=v"(r) : "v"(x)); return r;
}
__device__ inline unsigned cvt_pk_bf16(float lo, float hi) {
  unsigned r; asm("v_cvt_pk_bf16_f32 %0, %1, %2" : "=v"(r) : "v"(lo), "v"(hi)); return r;
}
// a <- [a.l0-31 | b.l0-31], b <- [a.l32-63 | b.l32-63]
__device__ inline void permlane32_swap(unsigned& a, unsigned& b) {
  asm volatile("v_permlane32_swap_b32 %0, %1" : "+v"(a), "+v"(b));
}
__device__ inline void gll16(const unsigned short* src, void* lds) {
  __builtin_amdgcn_global_load_lds((const __attribute__((address_space(1))) void*)src,
                                   (__attribute__((address_space(3))) void*)lds, 16, 0, 0);
}

// wf layout (fragment-major): B-frag for (col-tile ct, k-step s) of the 320x256
// combined weight: element (col C = ct*16+cl, k = s*32+gf*8+j) lives at
// wf[((ct*8+s)*64 + gf*16+cl)*8 + j]. A wave's B-load = 64 lanes x 16B contiguous.
__device__ inline size_t wf_addr(int C, int kk) {
  int ct = C >> 4, cl = C & 15, s = kk >> 5, gf = (kk >> 3) & 3, j = kk & 7;
  return ((size_t)((ct * 8 + s) * 64 + gf * 16 + cl)) * 8 + j;
}

// ---------------- kernel 0: FUSED weight prep (one launch) ----------------
// blocks 0-63: cast w_q^T*log2e | w_k^T into wf tiles 0-3 (unchanged r18 path).
// blocks 64-79: Wvo^T = Wo^T . Wv^T, 16 output rows per block. A (Wo^T slice,
// the transposed operand) is cast ONCE into LDS via coalesced 64B-segment loads;
// B (= wv, no transpose needed) is read fp32-direct with inline cvt_pk. 4 waves
// split the 16 col-tiles (4 each). Output written fragment-major to wf tiles 4-19.
__global__ __launch_bounds__(256) void prep_kernel(const float* __restrict__ wq,
                                                   const float* __restrict__ wk,
                                                   const float* __restrict__ wo,
                                                   const float* __restrict__ wv,
                                                   unsigned short* __restrict__ wf) {
  const int blk = blockIdx.x;
  if (blk < 64) {
    int i = blk * 256 + threadIdx.x;  // 16384 total
    int C = i >> 8, kk = i & 255;
    float v = (C < 32) ? wq[kk * 32 + C] * LOG2E : wk[kk * 32 + (C - 32)];
    wf[wf_addr(C, kk)] = f2bf(v);
    return;
  }
  // ---- Wvo GEMM block: rows m0..m0+15 of Wvo^T ----
  __shared__ unsigned short als[16 * 264];  // A tile, stride 264 (rotates banks)
  const int tid = threadIdx.x;
  const int l = tid & 63, w = tid >> 6;
  const int g = l >> 4, li = l & 15;
  const int m0 = (blk - 64) * 16;

  // stage A: als[row][k] = bf16(wo[k*256 + m0+row]); 16 scalar loads/thread,
  // each 16-thread group reads a contiguous 64B segment per k.
  {
    const int row = tid & 15, kb = tid >> 4;
#pragma unroll
    for (int j = 0; j < 16; ++j) {
      const int kk = kb * 16 + j;
      als[row * 264 + kk] = f2bf(wo[(size_t)kk * 256 + m0 + row]);
    }
  }
  __syncthreads();

  f32x4 acc[4] = {};  // wave w owns col-tiles w*4 .. w*4+3
  for (int kk = 0; kk < 256; kk += 32) {
    short8 a = *reinterpret_cast<const short8*>(&als[li * 264 + kk + g * 8]);
#pragma unroll
    for (int c = 0; c < 4; ++c) {
      const int ct = w * 4 + c;
      const float* bsrc = wv + (size_t)(ct * 16 + li) * 256 + kk + g * 8;
      f32x4 b0 = *reinterpret_cast<const f32x4*>(bsrc);
      f32x4 b1 = *reinterpret_cast<const f32x4*>(bsrc + 4);
      union { unsigned u[4]; short8 v; } Bf;
      Bf.u[0] = cvt_pk_bf16(b0[0], b0[1]); Bf.u[1] = cvt_pk_bf16(b0[2], b0[3]);
      Bf.u[2] = cvt_pk_bf16(b1[0], b1[1]); Bf.u[3] = cvt_pk_bf16(b1[2], b1[3]);
      acc[c] = __builtin_amdgcn_mfma_f32_16x16x32_bf16(a, Bf.v, acc[c], 0, 0, 0);
    }
  }
#pragma unroll
  for (int c = 0; c < 4; ++c) {
    const int ct = w * 4 + c;
#pragma unroll
    for (int r = 0; r < 4; ++r) {
      const int Cout = 64 + m0 + (g << 2) + r;
      const int kko = ct * 16 + li;
      wf[wf_addr(Cout, kko)] = f2bf(acc[c][r]);
    }
  }
}

// ---------------- kernel 1: fused QKVW projection (r13/r18, validated) ----------------
__global__ __launch_bounds__(256, 2) void qkv_kernel(const float* __restrict__ x,
                                                     const unsigned short* __restrict__ wf,
                                                     unsigned short* __restrict__ q,
                                                     unsigned short* __restrict__ k,
                                                     unsigned short* __restrict__ vwT) {
  __shared__ __align__(16) unsigned short xs[64 * 256];  // 32KB, swizzled
  const int tid = threadIdx.x;
  const int l = tid & 63, w = tid >> 6;
  const int bx = blockIdx.x;
  const int g = l >> 4, li = l & 15;
  const int m0 = bx * 64;

  const unsigned short* wfb = wf + (size_t)(w * 5) * 4096;  // wave's 5 col-tiles

  short8 BA[5], BB[5];
#pragma unroll
  for (int c = 0; c < 5; ++c)
    BA[c] = *reinterpret_cast<const short8*>(wfb + ((size_t)(c * 8 + 0) * 64 + l) * 8);
#pragma unroll
  for (int c = 0; c < 5; ++c)
    BB[c] = *reinterpret_cast<const short8*>(wfb + ((size_t)(c * 8 + 1) * 64 + l) * 8);

  {
    const int row = tid >> 2, qtr = tid & 3;
    const float* src = x + (size_t)(m0 + row) * 256 + qtr * 64;
    unsigned short* dstrow = xs + row * 256;
#pragma unroll
    for (int jj = 0; jj < 8; ++jj) {
      f32x4 a0 = *reinterpret_cast<const f32x4*>(src + jj * 8);
      f32x4 a1 = *reinterpret_cast<const f32x4*>(src + jj * 8 + 4);
      union { unsigned u[4]; ushort8 v; } P;
      P.u[0] = cvt_pk_bf16(a0[0], a0[1]); P.u[1] = cvt_pk_bf16(a0[2], a0[3]);
      P.u[2] = cvt_pk_bf16(a1[0], a1[1]); P.u[3] = cvt_pk_bf16(a1[2], a1[3]);
      const int blk = (qtr * 8 + jj) ^ (row & 7);
      *reinterpret_cast<ushort8*>(dstrow + blk * 8) = P.v;
    }
  }
  __syncthreads();  // xs ready; read-only hereafter

  f32x4 acc[4][5] = {};

#define QSTEP(S, BV, WN, PREF)                                                       \
  {                                                                                  \
    asm volatile("s_waitcnt vmcnt(" WN ")" ::: "memory");                            \
    __builtin_amdgcn_sched_barrier(0);                                               \
    short8 a_[4];                                                                    \
    _Pragma("unroll") for (int mt = 0; mt < 4; ++mt) {                               \
      const int row = mt * 16 + li;                                                  \
      a_[mt] = *reinterpret_cast<const short8*>(                                     \
          xs + row * 256 + ((((S) * 4 + g) ^ (row & 7)) << 3));                      \
    }                                                                                \
    _Pragma("unroll") for (int mt = 0; mt < 4; ++mt)                                 \
        _Pragma("unroll") for (int c = 0; c < 5; ++c)                                \
            acc[mt][c] = __builtin_amdgcn_mfma_f32_16x16x32_bf16(a_[mt], BV[c],      \
                                                                 acc[mt][c], 0, 0, 0); \
    if (PREF) {                                                                      \
      _Pragma("unroll") for (int c = 0; c < 5; ++c)                                  \
          BV[c] = *reinterpret_cast<const short8*>(                                  \
              wfb + ((size_t)(c * 8 + (S) + 2) * 64 + l) * 8);                       \
    }                                                                                \
  }

  QSTEP(0, BA, "5", true)
  QSTEP(1, BB, "5", true)
  QSTEP(2, BA, "5", true)
  QSTEP(3, BB, "5", true)
  QSTEP(4, BA, "5", true)
  QSTEP(5, BB, "5", true)
  QSTEP(6, BA, "5", false)
  QSTEP(7, BB, "0", false)
#undef QSTEP

  const int bb_ = bx >> 6;
#pragma unroll
  for (int mt = 0; mt < 4; ++mt) {
    const int nloc = (bx & 63) * 64 + mt * 16 + (g << 2);
#pragma unroll
    for (int c = 0; c < 5; ++c) {
      const int Cg = w * 5 + c;
      if (Cg < 2) {
        const int col = Cg * 16 + li;
#pragma unroll
        for (int r = 0; r < 4; ++r)
          q[((size_t)bb_ * N_ + nloc + r) * D_ + col] = f2bf(acc[mt][c][r]);
      } else if (Cg < 4) {
        const int col = (Cg - 2) * 16 + li;
#pragma unroll
        for (int r = 0; r < 4; ++r)
          k[((size_t)bb_ * N_ + nloc + r) * D_ + col] = f2bf(acc[mt][c][r]);
      } else {
        const int vc = Cg * 16 + li - 64;
        union { unsigned u[2]; ushort4v v; } P;
        P.u[0] = cvt_pk_bf16(acc[mt][c][0], acc[mt][c][1]);
        P.u[1] = cvt_pk_bf16(acc[mt][c][2], acc[mt][c][3]);
        *reinterpret_cast<ushort4v*>(&vwT[((size_t)bb_ * C_ + vc) * N_ + nloc]) = P.v;
      }
    }
  }
}

// ---------------- kernel 2: flash attention (r16/r18, frozen) ----------
__global__ __launch_bounds__(512, 2) void flash_kernel(const unsigned short* __restrict__ q,
                                                       const unsigned short* __restrict__ k,
                                                       const unsigned short* __restrict__ vwT,
                                                       const float* __restrict__ x,
                                                       float* __restrict__ out) {
  __shared__ __align__(16) char smem[147456];  // V 2grp x 2buf x 32KB | K @131072 2x2x4KB
  const int tid = threadIdx.x;
  const int l = tid & 63, w_ = tid >> 6;       // 0..7
  const int kvh = w_ >> 2, qg = w_ & 3;
  const int blk = blockIdx.x;
  const int b = blk & 7;
  const int qt = blk >> 3;                     // 0..31
  const int h = l >> 5, l31 = l & 31;
  const int R = kvh * 65536;

  const unsigned short* kb_ = k + (size_t)b * N_ * D_;
  const unsigned short* vb_ = vwT + (size_t)b * C_ * N_;

  const int qposb = qt * 128 + qg * 32;  // + l31
  const size_t qoff = ((size_t)b * N_ + qposb + l31) * D_ + h * 8;
  const short8 qb0 = *reinterpret_cast<const short8*>(q + qoff);
  const short8 qb1 = *reinterpret_cast<const short8*>(q + qoff + 16);
  asm volatile("s_waitcnt vmcnt(0)" ::: "memory");  // clean vm counter before staging

  const int vrow = l >> 3;
  const int vsrc = ((l & 7) ^ ((l >> 3) & 7)) << 3;  // elems
  const int krow = l >> 2;
  const int ksrc = ((l & 3) ^ ((l >> 3) & 3)) << 3;  // elems
  const int kvbase = kvh * 2048;

#define STAGE(BUF, KV0)                                                           \
  {                                                                               \
    char* vd = smem + R + (BUF) * 32768 + qg * 8192;                              \
    _Pragma("unroll") for (int t = 0; t < 8; ++t)                                 \
        gll16(vb_ + (size_t)(qg * 64 + t * 8 + vrow) * N_ + (KV0) + vsrc,         \
              vd + t * 1024);                                                     \
    gll16(kb_ + (size_t)((KV0) + qg * 16 + krow) * D_ + ksrc,                     \
          smem + 131072 + kvh * 8192 + (BUF) * 4096 + qg * 1024);                 \
  }

  f32x16 o[8] = {};  // [ct]: O^T (32c x 32q), c = ct*32 + ...
  float lsum = 0.f;
  const f32x16 z16 = {};
  const int kkey = (l31 >> 1) & 3;

  STAGE(0, kvbase)

  for (int i = 0; i < 32; ++i) {
    const int buf = i & 1;
    asm volatile("s_waitcnt vmcnt(0)" ::: "memory");  // chunk i landed (1 iter ago)
    __builtin_amdgcn_sched_barrier(0);
    __builtin_amdgcn_s_barrier();  // all waves' chunk-i loads landed; buf^1 reads done
    if (i < 31) STAGE(buf ^ 1, kvbase + (i + 1) * 64)
    const char* Vb = smem + R + buf * 32768;
    const char* Kb = smem + 131072 + kvh * 8192 + buf * 4096;
#pragma unroll
    for (int kvt = 0; kvt < 2; ++kvt) {
      const int krow32 = (kvt * 32 + l31) * 64;
      short8 ka0 = *reinterpret_cast<const short8*>(Kb + krow32 + (((0 + h) ^ kkey) << 4));
      short8 ka1 = *reinterpret_cast<const short8*>(Kb + krow32 + (((2 + h) ^ kkey) << 4));
      f32x16 s = __builtin_amdgcn_mfma_f32_32x32x16_bf16(ka0, qb0, z16, 0, 0, 0);
      s = __builtin_amdgcn_mfma_f32_32x32x16_bf16(ka1, qb1, s, 0, 0, 0);
#pragma unroll
      for (int r = 0; r < 16; ++r) s[r] = exp2_fast(s[r]);
      lsum += (((s[0] + s[1]) + (s[2] + s[3])) + ((s[4] + s[5]) + (s[6] + s[7]))) +
              (((s[8] + s[9]) + (s[10] + s[11])) + ((s[12] + s[13]) + (s[14] + s[15])));
      short8 pf0, pf1;
      {
        unsigned x0 = cvt_pk_bf16(s[0], s[1]),   y0 = cvt_pk_bf16(s[4], s[5]);
        unsigned x1 = cvt_pk_bf16(s[2], s[3]),   y1 = cvt_pk_bf16(s[6], s[7]);
        unsigned x2 = cvt_pk_bf16(s[8], s[9]),   y2 = cvt_pk_bf16(s[12], s[13]);
        unsigned x3 = cvt_pk_bf16(s[10], s[11]), y3 = cvt_pk_bf16(s[14], s[15]);
        permlane32_swap(x0, y0); permlane32_swap(x1, y1);
        permlane32_swap(x2, y2); permlane32_swap(x3, y3);
        union U { unsigned u[4]; short8 v; };
        U u0; u0.u[0] = x0; u0.u[1] = x1; u0.u[2] = y0; u0.u[3] = y1;  // kv 0-15
        U u1; u1.u[0] = x2; u1.u[1] = x3; u1.u[2] = y2; u1.u[3] = y3;  // kv 16-31
        pf0 = u0.v; pf1 = u1.v;
      }
      __builtin_amdgcn_s_setprio(1);
#pragma unroll
      for (int ct = 0; ct < 8; ++ct) {
        const int rl = ct * 32 + l31;
        const int vkey = rl & 7;
        const int rb = rl * 128;
        short8 va0 = *reinterpret_cast<const short8*>(Vb + rb + (((kvt * 4 + 0 + h) ^ vkey) << 4));
        short8 va1 = *reinterpret_cast<const short8*>(Vb + rb + (((kvt * 4 + 2 + h) ^ vkey) << 4));
        o[ct] = __builtin_amdgcn_mfma_f32_32x32x16_bf16(va0, pf0, o[ct], 0, 0, 0);
        o[ct] = __builtin_amdgcn_mfma_f32_32x32x16_bf16(va1, pf1, o[ct], 0, 0, 0);
      }
      __builtin_amdgcn_s_setprio(0);
    }
  }

  // ---- in-block kv-merge + normalize + residual + final store ----
  lsum += __shfl_xor(lsum, 32);
  __syncthreads();  // final chunk reads complete; LDS reusable
  float* lb = reinterpret_cast<float*>(smem + 131072);  // lsums[2][4][32] in K region
  if (h == 0) lb[kvh * 128 + qg * 32 + l31] = lsum;
  if (kvh == 1) {
    char* ob = smem + qg * 16384;  // wave slot: 64 bf16-pairs/lane, b128 lane-major
    int pg = 0;
#pragma unroll
    for (int ct = 0; ct < 8; ++ct)
#pragma unroll
      for (int jg = 0; jg < 2; ++jg) {
        u32x4 t;
#pragma unroll
        for (int e = 0; e < 4; ++e) {
          const int j = jg * 4 + e;
          t[e] = cvt_pk_bf16(o[ct][2 * j], o[ct][2 * j + 1]);
        }
        *reinterpret_cast<u32x4*>(ob + pg * 1024 + l * 16) = t;
        ++pg;
      }
  }
  __syncthreads();
  if (kvh == 0) {
    const float inv = 1.0f / (lb[qg * 32 + l31] + lb[128 + qg * 32 + l31]);
    const char* ob = smem + qg * 16384;
    int pg = 0;
#pragma unroll
    for (int ct = 0; ct < 8; ++ct)
#pragma unroll
      for (int jg = 0; jg < 2; ++jg) {
        u32x4 t = *reinterpret_cast<const u32x4*>(ob + pg * 1024 + l * 16);
        ++pg;
#pragma unroll
        for (int e = 0; e < 4; ++e) {
          const int j = jg * 4 + e;
          o[ct][2 * j]     += bf2f((unsigned short)(t[e] & 0xffffu));
          o[ct][2 * j + 1] += bf2f((unsigned short)(t[e] >> 16));
        }
      }
    const size_t rowbase = ((size_t)b * N_ + qposb + l31) * C_;
#pragma unroll
    for (int ct = 0; ct < 8; ++ct)
#pragma unroll
      for (int j = 0; j < 8; ++j) {
        const int c = ct * 32 + 2 * (j & 1) + 8 * (j >> 1) + 4 * h;
        f32x2 xr = *reinterpret_cast<const f32x2*>(x + rowbase + c);
        f32x2 t;
        t[0] = o[ct][2 * j] * inv + xr[0];
        t[1] = o[ct][2 * j + 1] * inv + xr[1];
        *reinterpret_cast<f32x2*>(out + rowbase + c) = t;
      }
  }
#undef STAGE
}

extern "C" void kernel_launch(void* const* d_in, const int* in_sizes, int n_in,
                              void* d_out, int out_size, void* d_ws, size_t ws_size,
                              hipStream_t stream) {
  const float* x  = (const float*)d_in[0];
  const float* wq = (const float*)d_in[1];
  const float* wk = (const float*)d_in[2];
  const float* wv = (const float*)d_in[3];
  const float* wo = (const float*)d_in[4];
  float* out = (float*)d_out;
  char* ws = (char*)d_ws;
  unsigned short* wf  = (unsigned short*)(ws + 0);        // 163840 B (frag-major W)
  unsigned short* q   = (unsigned short*)(ws + 163840);   // 2 MB
  unsigned short* k   = (unsigned short*)(ws + 2260992);  // 2 MB
  unsigned short* vwT = (unsigned short*)(ws + 4358144);  // 16 MB (total ~20.2 MB)

  prep_kernel<<<80, 256, 0, stream>>>(wq, wk, wo, wv, wf);
  qkv_kernel<<<512, 256, 0, stream>>>(x, wf, q, k, vwT);
  flash_kernel<<<256, 512, 0, stream>>>(q, k, vwT, x, out);
}